// Round 10
// baseline (222.839 us; speedup 1.0000x reference)
//
#include <hip/hip_runtime.h>
#include <hip/hip_bf16.h>
#include <math.h>

#define T_TOK 8192
#define D_MODEL 2048
#define N_EXP 16
#define CAP 512
#define NSEG (T_TOK / 64)           // 128
#define SMSTRIDE 130                // u64 stride per expert row
#define KHALF 1024                  // K per gemm block (K-split 2)

// ws layout (bytes):
// partial:  0       .. 1048576   float[2][T_TOK][16]
// pref:     1048576 .. +65536    u64[T_TOK]
// probs:    1114112 .. +524288   float[T_TOK][16]
// segmask0: 1638400 .. +16384    u64[16][128]
// evt:      1654784 .. +128      int[32] (evp[16], evf[16])
// flags:    1654912 .. +2048     int[32][16] (lookback, poison-safe)

__device__ __forceinline__ unsigned int f2ord(float f) {
    unsigned int b = __float_as_uint(f);
    return (b & 0x80000000u) ? ~b : (b | 0x80000000u);
}

// ---------------- Kernel 1: GEMM, K-split 2, W-half staged once, barrier-free K-loop ----
// 1024 blocks x 512 thr (8 waves). ks = blk&1 (K half), tile = blk>>1 (16 tokens).
// Wave owns 2 tokens; lane slices K. 64 KB LDS -> 2 blocks/CU -> 16 waves/CU.
__global__ __launch_bounds__(512, 2) void gemm_aff_kernel(
    const float* __restrict__ feat, const float* __restrict__ W,
    float* __restrict__ partial)
{
    __shared__ float w_lds[N_EXP * KHALF];   // 64 KB

    const int tid  = threadIdx.x;
    const int wave = tid >> 6, lane = tid & 63;
    const int ks   = blockIdx.x & 1;
    const int tile = blockIdx.x >> 1;
    const int k0   = ks * KHALF;
    const int tbase = tile * 16 + wave * 2;

    // stage this K-half of W: 4096 float4, 8 per thread, coalesced
    float4 wst[8];
    #pragma unroll
    for (int q = 0; q < 8; ++q) {
        int i4 = tid + q * 512;
        int e = i4 >> 8, kk4 = i4 & 255;
        wst[q] = ((const float4*)(W + (size_t)e * D_MODEL + k0))[kk4];
    }
    #pragma unroll
    for (int q = 0; q < 8; ++q)
        ((float4*)w_lds)[tid + q * 512] = wst[q];

    const float* fb = feat + (size_t)tbase * D_MODEL + k0 + lane * 4;

    float acc[32];   // acc[r*16+e]
    #pragma unroll
    for (int i = 0; i < 32; ++i) acc[i] = 0.f;

    float4 cur[2], nxt[2];
    #pragma unroll
    for (int r = 0; r < 2; ++r)
        cur[r] = *(const float4*)(fb + (size_t)r * D_MODEL);

    __syncthreads();   // W staged; no further barriers

    #pragma unroll
    for (int j = 0; j < 4; ++j) {           // 4 chunks of 256 floats
        if (j < 3) {
            #pragma unroll
            for (int r = 0; r < 2; ++r)
                nxt[r] = *(const float4*)(fb + (size_t)r * D_MODEL + (j + 1) * 256);
        }
        #pragma unroll
        for (int e = 0; e < N_EXP; ++e) {
            float4 wv = *(const float4*)&w_lds[e * KHALF + j * 256 + lane * 4];
            #pragma unroll
            for (int r = 0; r < 2; ++r) {
                acc[r * 16 + e] += cur[r].x * wv.x;
                acc[r * 16 + e] += cur[r].y * wv.y;
                acc[r * 16 + e] += cur[r].z * wv.z;
                acc[r * 16 + e] += cur[r].w * wv.w;
            }
        }
        #pragma unroll
        for (int r = 0; r < 2; ++r) cur[r] = nxt[r];
    }

    // halving butterfly: 32 slots -> 1, then fold lane bit 5 (verified r8/r9)
    #pragma unroll
    for (int step = 0; step < 5; ++step) {
        const int m    = 1 << step;
        const int half = 32 >> (step + 1);
        const bool hi  = (lane & m) != 0;
        #pragma unroll
        for (int jj = 0; jj < half; ++jj) {
            float send = hi ? acc[jj] : acc[jj + half];
            float recv = __shfl_xor(send, m, 64);
            acc[jj] = (hi ? acc[jj + half] : acc[jj]) + recv;
        }
    }
    acc[0] += __shfl_xor(acc[0], 32, 64);
    const int slot = ((lane & 1) << 4) | (((lane >> 1) & 1) << 3) | (((lane >> 2) & 1) << 2)
                   | (((lane >> 3) & 1) << 1) | ((lane >> 4) & 1);
    if (lane < 32) {
        const int r = slot >> 4, e = slot & 15;
        partial[((size_t)ks * T_TOK + tbase + r) * N_EXP + e] = acc[0];
    }
}

// ---------------- Kernel 2: sum K-halves + bias + softmax + pref + segment masks ----
// 128 blocks x 64 thr: block b == segment b.
__global__ __launch_bounds__(64) void finalize_kernel(
    const float* __restrict__ partial, const float* __restrict__ bias,
    unsigned long long* __restrict__ pref, float* __restrict__ probs,
    unsigned long long* __restrict__ segmask0)
{
    const int lane = threadIdx.x;
    const int t = blockIdx.x * 64 + lane;

    float aff[N_EXP];
    {
        const float4* p0 = (const float4*)(partial + (size_t)t * N_EXP);
        const float4* p1 = (const float4*)(partial + ((size_t)T_TOK + t) * N_EXP);
        #pragma unroll
        for (int q = 0; q < 4; ++q) {
            float4 a = p0[q], b = p1[q];
            aff[q*4+0] = a.x + b.x; aff[q*4+1] = a.y + b.y;
            aff[q*4+2] = a.z + b.z; aff[q*4+3] = a.w + b.w;
        }
    }
    #pragma unroll
    for (int e = 0; e < N_EXP; ++e) aff[e] += bias[e];

    float m = aff[0];
    #pragma unroll
    for (int e = 1; e < N_EXP; ++e) m = fmaxf(m, aff[e]);
    float s = 0.f;
    #pragma unroll
    for (int e = 0; e < N_EXP; ++e) s += __expf(aff[e] - m);

    float4* pr = (float4*)(probs + (size_t)t * N_EXP);
    #pragma unroll
    for (int q = 0; q < 4; ++q) {
        float4 v;
        v.x = __expf(aff[q*4+0] - m) / s;
        v.y = __expf(aff[q*4+1] - m) / s;
        v.z = __expf(aff[q*4+2] - m) / s;
        v.w = __expf(aff[q*4+3] - m) / s;
        pr[q] = v;
    }

    unsigned long long key[N_EXP];
    #pragma unroll
    for (int j = 0; j < N_EXP; ++j)
        key[j] = ((unsigned long long)f2ord(aff[j]) << 4) | (unsigned long long)(15 - j);
    unsigned long long pk = 0ull;
    unsigned int used = 0;
    for (int r = 0; r < N_EXP; ++r) {
        unsigned long long bk = 0ull; int be = 0;
        for (int j = 0; j < N_EXP; ++j)
            if (!((used >> j) & 1u) && key[j] > bk) { bk = key[j]; be = j; }
        used |= (1u << be);
        pk = (pk << 4) | (unsigned long long)be;
    }
    pref[t] = pk;

    const int c = (int)(pk >> 60);
    #pragma unroll
    for (int e = 0; e < N_EXP; ++e) {
        unsigned long long mm = __ballot(c == e);
        if (lane == e) segmask0[(size_t)e * NSEG + blockIdx.x] = mm;
    }
}

// ---------------- Kernel 3: fill-event schedule (1 block, 512 thr) ----------------
__global__ __launch_bounds__(512) void events_kernel(
    const unsigned long long* __restrict__ pref,
    const unsigned long long* __restrict__ segmask0,
    int* __restrict__ evt)
{
    __shared__ unsigned long long prefL[T_TOK];               // 64 KB
    __shared__ unsigned long long segmask[N_EXP * SMSTRIDE];  // 16.6 KB
    __shared__ unsigned short queue[T_TOK];                   // 16 KB
    __shared__ int rem_cap[N_EXP], fparr[N_EXP];
    __shared__ int s_qn;
    __shared__ int evpL[N_EXP], evfL[N_EXP];

    const int tid  = threadIdx.x;
    const int wave = tid >> 6, lane = tid & 63;
    const unsigned long long lt_mask = (1ull << lane) - 1ull;

    for (int i = tid; i < T_TOK; i += 512) prefL[i] = pref[i];
    for (int i = tid; i < N_EXP * NSEG; i += 512)
        segmask[(i >> 7) * SMSTRIDE + (i & 127)] = segmask0[i];
    if (tid < N_EXP) rem_cap[tid] = CAP;
    __syncthreads();

    unsigned int avail = 0xFFFFu;   // wave-uniform, tracked per thread
    int seglo = 0;

    for (int round = 0; round < N_EXP; ++round) {
        // ---- A: packed pair-sum scan (experts wave, wave+8) + crossing locate
        const int e0 = wave, e1 = wave + 8;
        const int s0 = 2 * lane, s1 = s0 + 1;
        const int c00 = (s0 >= seglo) ? (int)__popcll(segmask[e0 * SMSTRIDE + s0]) : 0;
        const int c01 = (s1 >= seglo) ? (int)__popcll(segmask[e0 * SMSTRIDE + s1]) : 0;
        const int c10 = (s0 >= seglo) ? (int)__popcll(segmask[e1 * SMSTRIDE + s0]) : 0;
        const int c11 = (s1 >= seglo) ? (int)__popcll(segmask[e1 * SMSTRIDE + s1]) : 0;

        unsigned long long v = (unsigned long long)(unsigned)(c00 + c01)
                             | ((unsigned long long)(unsigned)(c10 + c11) << 32);
        unsigned long long inc = v;
        #pragma unroll
        for (int d = 1; d < 64; d <<= 1) {
            unsigned long long o = __shfl_up(inc, (unsigned)d, 64);
            if (lane >= d) inc += o;
        }
        const unsigned long long exc = inc - v;
        const int ex0 = (int)(exc & 0xffffffffull);
        const int ex1 = (int)(exc >> 32);

        #pragma unroll
        for (int ee = 0; ee < 2; ++ee) {
            const int e   = ee ? e1 : e0;
            const int exl = ee ? ex1 : ex0;
            const int ca  = ee ? c10 : c00;
            const int cb  = ee ? c11 : c01;
            int fp = 0x7FFFFFFF;
            if ((avail >> e) & 1u) {
                const int need = rem_cap[e];
                const bool cross = (exl < need) && (need <= exl + ca + cb);
                int sstar = 0, kk = 0;
                if (cross) {
                    if (need <= exl + ca) { sstar = s0; kk = need - exl; }
                    else                  { sstar = s1; kk = need - exl - ca; }
                }
                unsigned long long b = __ballot(cross);
                if (b) {
                    int l2 = __builtin_ctzll(b);
                    int ss = __shfl(sstar, l2, 64);
                    int k2 = __shfl(kk,    l2, 64);
                    unsigned long long mm = segmask[e * SMSTRIDE + ss];
                    int rr = (int)__popcll(mm & lt_mask);
                    bool hit = ((mm >> lane) & 1ull) && (rr == k2 - 1);
                    unsigned long long hb = __ballot(hit);
                    fp = ss * 64 + __builtin_ctzll(hb);
                }
            }
            if (lane == 0) fparr[e] = fp;
        }
        __syncthreads();   // barrier 1

        // ---- B: every thread computes min locally (no barrier)
        int pmin = 0x7FFFFFFF, fe = 0;
        #pragma unroll
        for (int e = 0; e < N_EXP; ++e) {
            int vv = fparr[e];
            if (vv < pmin) { pmin = vv; fe = e; }
        }
        const int segF = pmin >> 6;

        if (tid == 0) { evpL[round] = pmin; evfL[round] = fe; s_qn = 0; }

        // ---- C: per-wave prune + capacity update for its two experts
        {
            const int lsrc = segF >> 1;
            const int exF0 = __shfl(ex0, lsrc, 64), cF00 = __shfl(c00, lsrc, 64);
            const int exF1 = __shfl(ex1, lsrc, 64), cF10 = __shfl(c10, lsrc, 64);
            const int pF0 = (segF & 1) ? exF0 + cF00 : exF0;
            const int pF1 = (segF & 1) ? exF1 + cF10 : exF1;
            if (lane == 0) {
                unsigned long long mlep = ((pmin & 63) == 63) ? ~0ull
                                          : ((1ull << ((pmin & 63) + 1)) - 1ull);
                unsigned long long mm = segmask[e0 * SMSTRIDE + segF];
                rem_cap[e0] -= pF0 + (int)__popcll(mm & mlep);
                segmask[e0 * SMSTRIDE + segF] = mm & ~mlep;
                mm = segmask[e1 * SMSTRIDE + segF];
                rem_cap[e1] -= pF1 + (int)__popcll(mm & mlep);
                segmask[e1 * SMSTRIDE + segF] = mm & ~mlep;
            }
        }
        __syncthreads();   // barrier 2 (prune + qn reset visible)

        // ---- D: queue-based rewalk of the filled expert's tail tokens
        if (round < N_EXP - 1) {
            const unsigned int navail = avail & ~(1u << fe);
            if (tid >= segF && tid < NSEG) {
                unsigned long long mm = segmask[fe * SMSTRIDE + tid];
                if (mm) {
                    segmask[fe * SMSTRIDE + tid] = 0ull;
                    int n = (int)__popcll(mm);
                    int off = atomicAdd(&s_qn, n);
                    int base = tid << 6;
                    while (mm) {
                        int i = __builtin_ctzll(mm); mm &= mm - 1ull;
                        queue[off++] = (unsigned short)(base | i);
                    }
                }
            }
            __syncthreads();   // barrier 3
            const int qn = s_qn;
            for (int qi = tid; qi < qn; qi += 512) {
                int ent = queue[qi];
                int s = ent >> 6, i = ent & 63;
                unsigned long long pp = prefL[s * 64 + i];
                int e2 = (int)(pp >> 60);
                while (!((navail >> e2) & 1u)) { pp <<= 4; e2 = (int)(pp >> 60); }
                atomicOr(&segmask[e2 * SMSTRIDE + s], 1ull << i);
            }
            __syncthreads();   // barrier 4
        }

        avail &= ~(1u << fe);
        seglo = segF;
    }

    if (tid < N_EXP) { evt[tid] = evpL[tid]; evt[N_EXP + tid] = evfL[tid]; }
}

// ---------------- Kernel 4: resolve (choice + ranks + writes), decoupled lookback ----
// 32 blocks x 256 thr. flags[b][e] published as 0x40000000|count (poison 0xAAAAAAAA
// is negative with bit30=0, so the poll predicate rejects it).
__global__ __launch_bounds__(256) void resolve_kernel(
    const unsigned long long* __restrict__ pref, const int* __restrict__ evt,
    const float* __restrict__ probs, int* __restrict__ flags,
    float* __restrict__ out0, float* __restrict__ out1)
{
    __shared__ int evp[N_EXP], evf[N_EXP];
    __shared__ int sc[4][N_EXP];
    __shared__ int base[N_EXP];
    const int tid = threadIdx.x, b = blockIdx.x;
    const int wave = tid >> 6, lane = tid & 63;
    const unsigned long long lt_mask = (1ull << lane) - 1ull;

    if (tid < N_EXP) evp[tid] = evt[tid];
    else if (tid < 2 * N_EXP) evf[tid - N_EXP] = evt[tid];
    __syncthreads();

    const int t = b * 256 + tid;
    unsigned int mask = 0xFFFFu;
    #pragma unroll
    for (int j = 0; j < N_EXP; ++j)
        if (evp[j] < t) mask &= ~(1u << evf[j]);

    unsigned long long pp = pref[t];
    int c = (int)(pp >> 60);
    while (!((mask >> c) & 1u)) { pp <<= 4; c = (int)(pp >> 60); }

    unsigned long long own = 0ull;
    #pragma unroll
    for (int e2 = 0; e2 < N_EXP; ++e2) {
        unsigned long long mm = __ballot(c == e2);
        if (c == e2) own = mm;
        if (lane == e2) sc[wave][e2] = (int)__popcll(mm);
    }
    __syncthreads();

    if (tid < N_EXP) {
        int tot = sc[0][tid] + sc[1][tid] + sc[2][tid] + sc[3][tid];
        __hip_atomic_store(&flags[b * N_EXP + tid], 0x40000000 | tot,
                           __ATOMIC_RELEASE, __HIP_MEMORY_SCOPE_AGENT);
        int s = 0;
        for (int b2 = 0; b2 < b; ++b2) {
            int vv;
            do {
                vv = __hip_atomic_load(&flags[b2 * N_EXP + tid],
                                       __ATOMIC_ACQUIRE, __HIP_MEMORY_SCOPE_AGENT);
            } while (vv < 0 || !(vv & 0x40000000));
            s += vv & 0xFFFF;
        }
        base[tid] = s;
    }
    __syncthreads();

    int rank = (int)__popcll(own & lt_mask);
    for (int w2 = 0; w2 < wave; ++w2) rank += sc[w2][c];
    const int pos = base[c] + rank;
    out0[c * CAP + pos] = (float)t;
    out1[t] = probs[(size_t)t * N_EXP + c];
}

extern "C" void kernel_launch(void* const* d_in, const int* in_sizes, int n_in,
                              void* d_out, int out_size, void* d_ws, size_t ws_size,
                              hipStream_t stream) {
    const float* feat = (const float*)d_in[0];
    const float* W    = (const float*)d_in[1];
    const float* bias = (const float*)d_in[2];

    float* out = (float*)d_out;
    char*  ws  = (char*)d_ws;

    float* partial               = (float*)ws;
    unsigned long long* pref     = (unsigned long long*)(ws + 1048576);
    float* probs                 = (float*)(ws + 1114112);
    unsigned long long* segmask0 = (unsigned long long*)(ws + 1638400);
    int* evt                     = (int*)(ws + 1654784);
    int* flags                   = (int*)(ws + 1654912);

    hipLaunchKernelGGL(gemm_aff_kernel, dim3(1024), dim3(512), 0, stream,
                       feat, W, partial);
    hipLaunchKernelGGL(finalize_kernel, dim3(NSEG), dim3(64), 0, stream,
                       partial, bias, pref, probs, segmask0);
    hipLaunchKernelGGL(events_kernel, dim3(1), dim3(512), 0, stream,
                       pref, segmask0, evt);
    hipLaunchKernelGGL(resolve_kernel, dim3(32), dim3(256), 0, stream,
                       pref, evt, probs, flags, out, out + T_TOK);
}